// Round 7
// baseline (237.718 us; speedup 1.0000x reference)
//
#include <hip/hip_runtime.h>
#include <hip/hip_bf16.h>
#include <math.h>

#define B_SZ 8
#define SEQ 2048
#define DIM 512

typedef __attribute__((ext_vector_type(8))) short bf16x8;
typedef __attribute__((ext_vector_type(8))) unsigned short u16x8;
typedef __attribute__((ext_vector_type(4))) float f32x4;

#define GLOBAL_AS __attribute__((address_space(1)))
#define LDS_AS __attribute__((address_space(3)))

__device__ __forceinline__ unsigned short f2bf(float f) {
    unsigned int u = __builtin_bit_cast(unsigned int, f);
    u += 0x7fffu + ((u >> 16) & 1u);   // RNE
    return (unsigned short)(u >> 16);
}

__device__ __forceinline__ void load_lds16(const void* g, void* l) {
    __builtin_amdgcn_global_load_lds((const GLOBAL_AS unsigned int*)g,
                                     (LDS_AS unsigned int*)l, 16, 0, 0);
}

// ---- fused fp32->bf16 conversion for BOTH tensors + zero the row-sum buffer ----
__global__ __launch_bounds__(256)
void convert_kernel(const float* __restrict__ Q, const float* __restrict__ K,
                    unsigned short* __restrict__ Qb, unsigned short* __restrict__ Kb,
                    float* __restrict__ sums) {
    const int half = (int)(((size_t)B_SZ * SEQ * DIM) / 8 / 256);   // 4096
    const int bid = blockIdx.x;
    const int gi = bid * 256 + threadIdx.x;
    if (gi < B_SZ * SEQ) sums[gi] = 0.f;    // 16384 floats, blocks 0..63

    const float* src;
    unsigned short* dst;
    int i;
    if (bid < half) { src = Q; dst = Qb; i = gi; }
    else            { src = K; dst = Kb; i = gi - half * 256; }

    const float4* s = (const float4*)src;
    float4 a = s[2 * i];
    float4 b = s[2 * i + 1];
    u16x8 o;
    o[0] = f2bf(a.x); o[1] = f2bf(a.y); o[2] = f2bf(a.z); o[3] = f2bf(a.w);
    o[4] = f2bf(b.x); o[5] = f2bf(b.y); o[6] = f2bf(b.z); o[7] = f2bf(b.w);
    ((u16x8*)dst)[i] = o;
}

// ---- m97-structure NT GEMM, 128x128 tile, BK=64 (halved drain count), fused
// exp + row-sum epilogue. blockIdx.x = b -> one batch per XCD (L2 affinity,
// proven -20us in R4). BK=64: one K-iter stages 128x64 per tensor (16 KB),
// 8 iters instead of 16 -> half the vmcnt-drain+barrier pairs of BK=32.
// tk>tq blocks write the final zero tiles.
#define BM 128
#define BK 64
__global__ __launch_bounds__(256)
void logits_exp_mfma(const unsigned short* __restrict__ Qb, const unsigned short* __restrict__ Kb,
                     float* __restrict__ out, float* __restrict__ sums) {
    const int b = blockIdx.x, tk = blockIdx.y, tq = blockIdx.z;
    float* outb = out + (size_t)b * SEQ * SEQ;
    const int t = threadIdx.x;

    if (tk > tq) {
        // strictly-upper tile: final output is exactly 0 here
        const int r0 = t >> 5;          // 0..7
        const int c4 = t & 31;          // 0..31 (float4 column)
        const float4 z = {0.f, 0.f, 0.f, 0.f};
        float* base = outb + (size_t)(tq * BM) * SEQ + tk * BM;
#pragma unroll
        for (int it = 0; it < 16; ++it)
            *(float4*)(base + (size_t)(it * 8 + r0) * SEQ + c4 * 4) = z;
        return;
    }

    __shared__ __align__(16) unsigned short a_lds[BM * BK];  // 16 KiB
    __shared__ __align__(16) unsigned short b_lds[BM * BK];  // 16 KiB

    const int wave = t >> 6;
    const int lane = t & 63;
    const int l16 = lane & 15;
    const int quad = lane >> 4;
    const int wm = wave >> 1;      // 2x2 wave grid, each wave 64x64
    const int wn = wave & 1;

    const unsigned short* Qrow = Qb + ((size_t)b * SEQ + (size_t)tq * BM) * DIM;
    const unsigned short* Krow = Kb + ((size_t)b * SEQ + (size_t)tk * BM) * DIM;

    // staging geometry at BK=64: one global_load_lds = 64 lanes x 16B
    //   = 8 rows x 128B (one full 64-col bf16 row per 8 lanes)
    const int sr8 = lane >> 3;     // 0..7 row-within-instr
    const int g8 = lane & 7;       // 0..7 col-group (8 bf16 = 16B each)

    f32x4 acc[4][4];
#pragma unroll
    for (int i = 0; i < 4; i++)
#pragma unroll
        for (int j = 0; j < 4; j++) acc[i][j] = (f32x4){0.f, 0.f, 0.f, 0.f};

    for (int k0 = 0; k0 < DIM; k0 += BK) {
#pragma unroll
        for (int j = wave; j < 16; j += 4) {
            int row = j * 8 + sr8;
            load_lds16(Qrow + (size_t)row * DIM + k0 + g8 * 8, &a_lds[(j * 8) * BK]);
            load_lds16(Krow + (size_t)row * DIM + k0 + g8 * 8, &b_lds[(j * 8) * BK]);
        }
        __syncthreads();   // drains vmcnt (global_load_lds) + publishes LDS

#pragma unroll
        for (int ks = 0; ks < 2; ++ks) {
            bf16x8 af[4], bfr[4];
#pragma unroll
            for (int mi = 0; mi < 4; mi++) {
                const int row = wm * 64 + mi * 16 + l16;
                af[mi] = *(const bf16x8*)&a_lds[row * BK + ks * 32 + quad * 8];
            }
#pragma unroll
            for (int ni = 0; ni < 4; ni++) {
                const int row = wn * 64 + ni * 16 + l16;
                bfr[ni] = *(const bf16x8*)&b_lds[row * BK + ks * 32 + quad * 8];
            }
#pragma unroll
            for (int mi = 0; mi < 4; mi++)
#pragma unroll
                for (int ni = 0; ni < 4; ni++)
                    acc[mi][ni] = __builtin_amdgcn_mfma_f32_16x16x32_bf16(af[mi], bfr[ni], acc[mi][ni], 0, 0, 0);
        }
        __syncthreads();   // LDS reuse guard
    }

    // ---- fused epilogue: e = exp(x*scale) (masked on diagonal tile),
    //      store e, and atomically accumulate per-row sums ----
    const float scale = 0.02209708691207961f;  // 1/sqrt(2048)
    const bool diag = (tk == tq);
    float* sums_b = sums + (size_t)b * SEQ;

#pragma unroll
    for (int mi = 0; mi < 4; mi++) {
#pragma unroll
        for (int r = 0; r < 4; r++) {
            const int row_l = wm * 64 + mi * 16 + quad * 4 + r;   // 0..127
            const int row = tq * BM + row_l;
            float rsum = 0.f;
#pragma unroll
            for (int ni = 0; ni < 4; ni++) {
                const int col = tk * BM + wn * 64 + ni * 16 + l16;
                float e;
                if (diag && col > row) e = 0.f;
                else e = __expf(acc[mi][ni][r] * scale);
                outb[(size_t)row * SEQ + col] = e;
                rsum += e;
            }
            // reduce across l16 (xor 1,2,4,8 stays within the 16-lane group)
            rsum += __shfl_xor(rsum, 1);
            rsum += __shfl_xor(rsum, 2);
            rsum += __shfl_xor(rsum, 4);
            rsum += __shfl_xor(rsum, 8);
            if (l16 == 0) atomicAdd(&sums_b[row], rsum);   // device-scope
        }
    }
}

// ---- trivial normalization pass: p = e * (1/sum), lower triangle only ----
__global__ __launch_bounds__(256)
void scale_kernel(float* __restrict__ out, const float* __restrict__ sums) {
    const int q = blockIdx.x & (SEQ - 1);
    const int b = blockIdx.x >> 11;
    float* row = out + ((size_t)b * SEQ + q) * SEQ;
    const float inv = 1.0f / sums[blockIdx.x];   // blockIdx.x == b*SEQ + q
    const int n = q + 1;
    const int t = threadIdx.x;
#pragma unroll
    for (int j = 0; j < 2; ++j) {
        int k0 = (t + j * 256) * 4;
        if (k0 < n) {
            float4 x = *(const float4*)(row + k0);
            x.x *= inv; x.y *= inv; x.z *= inv; x.w *= inv;
            *(float4*)(row + k0) = x;   // elements past q in this float4 are e=0 -> stay 0
        }
    }
}

// ==================== small-ws fallback path (round-1 flow) ====================
#define TS 64
#define DC 128
#define LSTRIDE (DC + 8)
__global__ __launch_bounds__(256)
void logits_fallback(const float* __restrict__ Q, const float* __restrict__ K,
                     float* __restrict__ out) {
    const int tk = blockIdx.x, tq = blockIdx.y, b = blockIdx.z;
    if (tk > tq) return;
    __shared__ __align__(16) unsigned short qs[TS * LSTRIDE];
    __shared__ __align__(16) unsigned short ks[TS * LSTRIDE];
    const int t = threadIdx.x;
    const int wave = t >> 6, lane = t & 63, l16 = lane & 15, quad = lane >> 4;
    const float* Qb = Q + ((size_t)b * SEQ + (size_t)tq * TS) * DIM;
    const float* Kb = K + ((size_t)b * SEQ + (size_t)tk * TS) * DIM;
    f32x4 acc[4];
#pragma unroll
    for (int i = 0; i < 4; i++) acc[i] = (f32x4){0.f, 0.f, 0.f, 0.f};
    for (int c = 0; c < DIM; c += DC) {
        __syncthreads();
#pragma unroll
        for (int i = 0; i < 8; i++) {
            int idx = t + i * 256;
            int row = idx >> 5, c4 = idx & 31;
            float4 qv = *(const float4*)(Qb + row * DIM + c + c4 * 4);
            float4 kv = *(const float4*)(Kb + row * DIM + c + c4 * 4);
            ushort4 qh = { f2bf(qv.x), f2bf(qv.y), f2bf(qv.z), f2bf(qv.w) };
            ushort4 kh = { f2bf(kv.x), f2bf(kv.y), f2bf(kv.z), f2bf(kv.w) };
            *(ushort4*)&qs[row * LSTRIDE + c4 * 4] = qh;
            *(ushort4*)&ks[row * LSTRIDE + c4 * 4] = kh;
        }
        __syncthreads();
#pragma unroll
        for (int d = 0; d < DC; d += 32) {
            bf16x8 afrag = *(const bf16x8*)&qs[(wave * 16 + l16) * LSTRIDE + d + quad * 8];
#pragma unroll
            for (int nt = 0; nt < 4; nt++) {
                bf16x8 bfrag = *(const bf16x8*)&ks[(nt * 16 + l16) * LSTRIDE + d + quad * 8];
                acc[nt] = __builtin_amdgcn_mfma_f32_16x16x32_bf16(afrag, bfrag, acc[nt], 0, 0, 0);
            }
        }
    }
    const float scale = 0.02209708691207961f;
    float* outb = out + (size_t)b * SEQ * SEQ;
#pragma unroll
    for (int nt = 0; nt < 4; nt++) {
        int col = tk * TS + nt * 16 + l16;
#pragma unroll
        for (int r = 0; r < 4; r++) {
            int row = tq * TS + wave * 16 + quad * 4 + r;
            outb[(size_t)row * SEQ + col] = acc[nt][r] * scale;
        }
    }
}

__global__ __launch_bounds__(256)
void softmax_kernel(float* __restrict__ out) {
    const int q = blockIdx.x & (SEQ - 1);
    const int b = blockIdx.x >> 11;
    float* row = out + ((size_t)b * SEQ + q) * SEQ;
    const int t = threadIdx.x;
    const int lane = t & 63;
    const int wave = t >> 6;
    const int n = q + 1;

    __shared__ float red[8];

    float4 v[2];
    float m = -INFINITY;
#pragma unroll
    for (int j = 0; j < 2; j++) {
        int k0 = (t + j * 256) * 4;
        if (k0 < n) {
            float4 x = *(const float4*)(row + k0);
            x.y = (k0 + 1 < n) ? x.y : -INFINITY;
            x.z = (k0 + 2 < n) ? x.z : -INFINITY;
            x.w = (k0 + 3 < n) ? x.w : -INFINITY;
            v[j] = x;
            m = fmaxf(m, fmaxf(fmaxf(x.x, x.y), fmaxf(x.z, x.w)));
        } else {
            v[j] = (float4){-INFINITY, -INFINITY, -INFINITY, -INFINITY};
        }
    }
#pragma unroll
    for (int off = 1; off < 64; off <<= 1) m = fmaxf(m, __shfl_xor(m, off));
    if (lane == 0) red[wave] = m;
    __syncthreads();
    m = fmaxf(fmaxf(red[0], red[1]), fmaxf(red[2], red[3]));

    float s = 0.f;
#pragma unroll
    for (int j = 0; j < 2; j++) {
        float4 e;
        e.x = __expf(v[j].x - m);
        e.y = __expf(v[j].y - m);
        e.z = __expf(v[j].z - m);
        e.w = __expf(v[j].w - m);
        v[j] = e;
        s += e.x + e.y + e.z + e.w;
    }
#pragma unroll
    for (int off = 1; off < 64; off <<= 1) s += __shfl_xor(s, off);
    if (lane == 0) red[4 + wave] = s;
    __syncthreads();
    s = red[4] + red[5] + red[6] + red[7];
    const float inv = 1.0f / s;

#pragma unroll
    for (int j = 0; j < 2; j++) {
        int k0 = (t + j * 256) * 4;
        float4 e = v[j];
        e.x *= inv; e.y *= inv; e.z *= inv; e.w *= inv;
        *(float4*)(row + k0) = e;
    }
}

extern "C" void kernel_launch(void* const* d_in, const int* in_sizes, int n_in,
                              void* d_out, int out_size, void* d_ws, size_t ws_size,
                              hipStream_t stream) {
    // setup_inputs order: {"K": ..., "Q": ...}
    const float* Kp = (const float*)d_in[0];
    const float* Qp = (const float*)d_in[1];
    float* out = (float*)d_out;

    const size_t nElem = (size_t)B_SZ * SEQ * DIM;                  // 8.4M per tensor
    const size_t bfBytes = nElem * sizeof(unsigned short);          // 16.8 MB
    const size_t sumsBytes = (size_t)B_SZ * SEQ * sizeof(float);    // 64 KB

    if (ws_size >= 2 * bfBytes + sumsBytes) {
        unsigned short* Qbf = (unsigned short*)d_ws;
        unsigned short* Kbf = Qbf + nElem;
        float* sums = (float*)((char*)d_ws + 2 * bfBytes);
        const int half = (int)(nElem / 8 / 256);                    // 4096
        convert_kernel<<<dim3(2 * half), dim3(256), 0, stream>>>(Qp, Kp, Qbf, Kbf, sums);
        // b in blockIdx.x: linear id % 8 == batch -> one batch per XCD (L2 affinity)
        logits_exp_mfma<<<dim3(B_SZ, SEQ / BM, SEQ / BM), dim3(256), 0, stream>>>(Qbf, Kbf, out, sums);
        scale_kernel<<<dim3(B_SZ * SEQ), dim3(256), 0, stream>>>(out, sums);
    } else {
        logits_fallback<<<dim3(SEQ / TS, SEQ / TS, B_SZ), dim3(256), 0, stream>>>(Qp, Kp, out);
        softmax_kernel<<<dim3(B_SZ * SEQ), dim3(256), 0, stream>>>(out);
    }
}

// Round 8
// 231.210 us; speedup vs baseline: 1.0281x; 1.0281x over previous
//
#include <hip/hip_runtime.h>
#include <hip/hip_bf16.h>
#include <math.h>

#define B_SZ 8
#define SEQ 2048
#define DIM 512

typedef __attribute__((ext_vector_type(8))) short bf16x8;
typedef __attribute__((ext_vector_type(8))) unsigned short u16x8;
typedef __attribute__((ext_vector_type(4))) float f32x4;

#define GLOBAL_AS __attribute__((address_space(1)))
#define LDS_AS __attribute__((address_space(3)))

__device__ __forceinline__ unsigned short f2bf(float f) {
    unsigned int u = __builtin_bit_cast(unsigned int, f);
    u += 0x7fffu + ((u >> 16) & 1u);   // RNE
    return (unsigned short)(u >> 16);
}

__device__ __forceinline__ void load_lds16(const void* g, void* l) {
    __builtin_amdgcn_global_load_lds((const GLOBAL_AS unsigned int*)g,
                                     (LDS_AS unsigned int*)l, 16, 0, 0);
}

// ---- fused fp32->bf16 conversion for BOTH tensors + zero the row-sum buffer ----
__global__ __launch_bounds__(256)
void convert_kernel(const float* __restrict__ Q, const float* __restrict__ K,
                    unsigned short* __restrict__ Qb, unsigned short* __restrict__ Kb,
                    float* __restrict__ sums) {
    const int half = (int)(((size_t)B_SZ * SEQ * DIM) / 8 / 256);   // 4096
    const int bid = blockIdx.x;
    const int gi = bid * 256 + threadIdx.x;
    if (gi < B_SZ * SEQ) sums[gi] = 0.f;    // 16384 floats, blocks 0..63

    const float* src;
    unsigned short* dst;
    int i;
    if (bid < half) { src = Q; dst = Qb; i = gi; }
    else            { src = K; dst = Kb; i = gi - half * 256; }

    const float4* s = (const float4*)src;
    float4 a = s[2 * i];
    float4 b = s[2 * i + 1];
    u16x8 o;
    o[0] = f2bf(a.x); o[1] = f2bf(a.y); o[2] = f2bf(a.z); o[3] = f2bf(a.w);
    o[4] = f2bf(b.x); o[5] = f2bf(b.y); o[6] = f2bf(b.z); o[7] = f2bf(b.w);
    ((u16x8*)dst)[i] = o;
}

// ---- m97-structure NT GEMM, 128x128 tile, BK=64, BOTH-SIDES XOR SWIZZLE ----
// R7 counters: MfmaUtil 8.9%, SQ_LDS_BANK_CONFLICT 6.68M -> fragment ds_read_b128
// was 8-way bank-conflicted (all lanes of a quad read the same 16B slot column
// at 128B row stride). Fix per guide G4 / rule #21:
//   - LDS dest stays LINEAR (global_load_lds requirement)
//   - global SOURCE col-group pre-swizzled: g8 ^ sr8  (involution per 8-row stripe)
//   - READ slot swizzled: (ks*4+quad) ^ (row&7)
// => each 8-lane quantum of a ds_read_b128 hits 32 distinct banks.
// blockIdx.x = b -> one batch per XCD (L2 affinity, proven -20us in R4).
#define BM 128
#define BK 64
__global__ __launch_bounds__(256)
void logits_exp_mfma(const unsigned short* __restrict__ Qb, const unsigned short* __restrict__ Kb,
                     float* __restrict__ out, float* __restrict__ sums) {
    const int b = blockIdx.x, tk = blockIdx.y, tq = blockIdx.z;
    float* outb = out + (size_t)b * SEQ * SEQ;
    const int t = threadIdx.x;

    if (tk > tq) {
        // strictly-upper tile: final output is exactly 0 here
        const int r0 = t >> 5;          // 0..7
        const int c4 = t & 31;          // 0..31 (float4 column)
        const float4 z = {0.f, 0.f, 0.f, 0.f};
        float* base = outb + (size_t)(tq * BM) * SEQ + tk * BM;
#pragma unroll
        for (int it = 0; it < 16; ++it)
            *(float4*)(base + (size_t)(it * 8 + r0) * SEQ + c4 * 4) = z;
        return;
    }

    __shared__ __align__(16) unsigned short a_lds[BM * BK];  // 16 KiB
    __shared__ __align__(16) unsigned short b_lds[BM * BK];  // 16 KiB

    const int wave = t >> 6;
    const int lane = t & 63;
    const int l16 = lane & 15;
    const int quad = lane >> 4;
    const int wm = wave >> 1;      // 2x2 wave grid, each wave 64x64
    const int wn = wave & 1;

    const unsigned short* Qrow = Qb + ((size_t)b * SEQ + (size_t)tq * BM) * DIM;
    const unsigned short* Krow = Kb + ((size_t)b * SEQ + (size_t)tk * BM) * DIM;

    // staging geometry at BK=64: one global_load_lds = 64 lanes x 16B
    //   = 8 rows x 128B. Pre-swizzled source col-group: g8 ^ sr8.
    const int sr8 = lane >> 3;     // 0..7 row-within-instr
    const int gsw = (lane & 7) ^ sr8;   // swizzled source col-group (16B units)

    f32x4 acc[4][4];
#pragma unroll
    for (int i = 0; i < 4; i++)
#pragma unroll
        for (int j = 0; j < 4; j++) acc[i][j] = (f32x4){0.f, 0.f, 0.f, 0.f};

    for (int k0 = 0; k0 < DIM; k0 += BK) {
#pragma unroll
        for (int j = wave; j < 16; j += 4) {
            int row = j * 8 + sr8;
            load_lds16(Qrow + (size_t)row * DIM + k0 + (gsw << 3), &a_lds[(j * 8) * BK]);
            load_lds16(Krow + (size_t)row * DIM + k0 + (gsw << 3), &b_lds[(j * 8) * BK]);
        }
        __syncthreads();   // drains vmcnt (global_load_lds) + publishes LDS

#pragma unroll
        for (int ks = 0; ks < 2; ++ks) {
            bf16x8 af[4], bfr[4];
#pragma unroll
            for (int mi = 0; mi < 4; mi++) {
                const int row = wm * 64 + mi * 16 + l16;
                const int slot = ((ks << 2) | quad) ^ (row & 7);   // swizzled read
                af[mi] = *(const bf16x8*)&a_lds[row * BK + (slot << 3)];
            }
#pragma unroll
            for (int ni = 0; ni < 4; ni++) {
                const int row = wn * 64 + ni * 16 + l16;
                const int slot = ((ks << 2) | quad) ^ (row & 7);
                bfr[ni] = *(const bf16x8*)&b_lds[row * BK + (slot << 3)];
            }
#pragma unroll
            for (int mi = 0; mi < 4; mi++)
#pragma unroll
                for (int ni = 0; ni < 4; ni++)
                    acc[mi][ni] = __builtin_amdgcn_mfma_f32_16x16x32_bf16(af[mi], bfr[ni], acc[mi][ni], 0, 0, 0);
        }
        __syncthreads();   // LDS reuse guard
    }

    // ---- fused epilogue: e = exp(x*scale) (masked on diagonal tile),
    //      store e, and atomically accumulate per-row sums ----
    const float scale = 0.02209708691207961f;  // 1/sqrt(2048)
    const bool diag = (tk == tq);
    float* sums_b = sums + (size_t)b * SEQ;

#pragma unroll
    for (int mi = 0; mi < 4; mi++) {
#pragma unroll
        for (int r = 0; r < 4; r++) {
            const int row_l = wm * 64 + mi * 16 + quad * 4 + r;   // 0..127
            const int row = tq * BM + row_l;
            float rsum = 0.f;
#pragma unroll
            for (int ni = 0; ni < 4; ni++) {
                const int col = tk * BM + wn * 64 + ni * 16 + l16;
                float e;
                if (diag && col > row) e = 0.f;
                else e = __expf(acc[mi][ni][r] * scale);
                outb[(size_t)row * SEQ + col] = e;
                rsum += e;
            }
            // reduce across l16 (xor 1,2,4,8 stays within the 16-lane group)
            rsum += __shfl_xor(rsum, 1);
            rsum += __shfl_xor(rsum, 2);
            rsum += __shfl_xor(rsum, 4);
            rsum += __shfl_xor(rsum, 8);
            if (l16 == 0) atomicAdd(&sums_b[row], rsum);   // device-scope
        }
    }
}

// ---- trivial normalization pass: p = e * (1/sum), lower triangle only ----
__global__ __launch_bounds__(256)
void scale_kernel(float* __restrict__ out, const float* __restrict__ sums) {
    const int q = blockIdx.x & (SEQ - 1);
    const int b = blockIdx.x >> 11;
    float* row = out + ((size_t)b * SEQ + q) * SEQ;
    const float inv = 1.0f / sums[blockIdx.x];   // blockIdx.x == b*SEQ + q
    const int n = q + 1;
    const int t = threadIdx.x;
#pragma unroll
    for (int j = 0; j < 2; ++j) {
        int k0 = (t + j * 256) * 4;
        if (k0 < n) {
            float4 x = *(const float4*)(row + k0);
            x.x *= inv; x.y *= inv; x.z *= inv; x.w *= inv;
            *(float4*)(row + k0) = x;   // elements past q in this float4 are e=0 -> stay 0
        }
    }
}

// ==================== small-ws fallback path (round-1 flow) ====================
#define TS 64
#define DC 128
#define LSTRIDE (DC + 8)
__global__ __launch_bounds__(256)
void logits_fallback(const float* __restrict__ Q, const float* __restrict__ K,
                     float* __restrict__ out) {
    const int tk = blockIdx.x, tq = blockIdx.y, b = blockIdx.z;
    if (tk > tq) return;
    __shared__ __align__(16) unsigned short qs[TS * LSTRIDE];
    __shared__ __align__(16) unsigned short ks[TS * LSTRIDE];
    const int t = threadIdx.x;
    const int wave = t >> 6, lane = t & 63, l16 = lane & 15, quad = lane >> 4;
    const float* Qb = Q + ((size_t)b * SEQ + (size_t)tq * TS) * DIM;
    const float* Kb = K + ((size_t)b * SEQ + (size_t)tk * TS) * DIM;
    f32x4 acc[4];
#pragma unroll
    for (int i = 0; i < 4; i++) acc[i] = (f32x4){0.f, 0.f, 0.f, 0.f};
    for (int c = 0; c < DIM; c += DC) {
        __syncthreads();
#pragma unroll
        for (int i = 0; i < 8; i++) {
            int idx = t + i * 256;
            int row = idx >> 5, c4 = idx & 31;
            float4 qv = *(const float4*)(Qb + row * DIM + c + c4 * 4);
            float4 kv = *(const float4*)(Kb + row * DIM + c + c4 * 4);
            ushort4 qh = { f2bf(qv.x), f2bf(qv.y), f2bf(qv.z), f2bf(qv.w) };
            ushort4 kh = { f2bf(kv.x), f2bf(kv.y), f2bf(kv.z), f2bf(kv.w) };
            *(ushort4*)&qs[row * LSTRIDE + c4 * 4] = qh;
            *(ushort4*)&ks[row * LSTRIDE + c4 * 4] = kh;
        }
        __syncthreads();
#pragma unroll
        for (int d = 0; d < DC; d += 32) {
            bf16x8 afrag = *(const bf16x8*)&qs[(wave * 16 + l16) * LSTRIDE + d + quad * 8];
#pragma unroll
            for (int nt = 0; nt < 4; nt++) {
                bf16x8 bfrag = *(const bf16x8*)&ks[(nt * 16 + l16) * LSTRIDE + d + quad * 8];
                acc[nt] = __builtin_amdgcn_mfma_f32_16x16x32_bf16(afrag, bfrag, acc[nt], 0, 0, 0);
            }
        }
    }
    const float scale = 0.02209708691207961f;
    float* outb = out + (size_t)b * SEQ * SEQ;
#pragma unroll
    for (int nt = 0; nt < 4; nt++) {
        int col = tk * TS + nt * 16 + l16;
#pragma unroll
        for (int r = 0; r < 4; r++) {
            int row = tq * TS + wave * 16 + quad * 4 + r;
            outb[(size_t)row * SEQ + col] = acc[nt][r] * scale;
        }
    }
}

__global__ __launch_bounds__(256)
void softmax_kernel(float* __restrict__ out) {
    const int q = blockIdx.x & (SEQ - 1);
    const int b = blockIdx.x >> 11;
    float* row = out + ((size_t)b * SEQ + q) * SEQ;
    const int t = threadIdx.x;
    const int lane = t & 63;
    const int wave = t >> 6;
    const int n = q + 1;

    __shared__ float red[8];

    float4 v[2];
    float m = -INFINITY;
#pragma unroll
    for (int j = 0; j < 2; j++) {
        int k0 = (t + j * 256) * 4;
        if (k0 < n) {
            float4 x = *(const float4*)(row + k0);
            x.y = (k0 + 1 < n) ? x.y : -INFINITY;
            x.z = (k0 + 2 < n) ? x.z : -INFINITY;
            x.w = (k0 + 3 < n) ? x.w : -INFINITY;
            v[j] = x;
            m = fmaxf(m, fmaxf(fmaxf(x.x, x.y), fmaxf(x.z, x.w)));
        } else {
            v[j] = (float4){-INFINITY, -INFINITY, -INFINITY, -INFINITY};
        }
    }
#pragma unroll
    for (int off = 1; off < 64; off <<= 1) m = fmaxf(m, __shfl_xor(m, off));
    if (lane == 0) red[wave] = m;
    __syncthreads();
    m = fmaxf(fmaxf(red[0], red[1]), fmaxf(red[2], red[3]));

    float s = 0.f;
#pragma unroll
    for (int j = 0; j < 2; j++) {
        float4 e;
        e.x = __expf(v[j].x - m);
        e.y = __expf(v[j].y - m);
        e.z = __expf(v[j].z - m);
        e.w = __expf(v[j].w - m);
        v[j] = e;
        s += e.x + e.y + e.z + e.w;
    }
#pragma unroll
    for (int off = 1; off < 64; off <<= 1) s += __shfl_xor(s, off);
    if (lane == 0) red[4 + wave] = s;
    __syncthreads();
    s = red[4] + red[5] + red[6] + red[7];
    const float inv = 1.0f / s;

#pragma unroll
    for (int j = 0; j < 2; j++) {
        int k0 = (t + j * 256) * 4;
        float4 e = v[j];
        e.x *= inv; e.y *= inv; e.z *= inv; e.w *= inv;
        *(float4*)(row + k0) = e;
    }
}

extern "C" void kernel_launch(void* const* d_in, const int* in_sizes, int n_in,
                              void* d_out, int out_size, void* d_ws, size_t ws_size,
                              hipStream_t stream) {
    // setup_inputs order: {"K": ..., "Q": ...}
    const float* Kp = (const float*)d_in[0];
    const float* Qp = (const float*)d_in[1];
    float* out = (float*)d_out;

    const size_t nElem = (size_t)B_SZ * SEQ * DIM;                  // 8.4M per tensor
    const size_t bfBytes = nElem * sizeof(unsigned short);          // 16.8 MB
    const size_t sumsBytes = (size_t)B_SZ * SEQ * sizeof(float);    // 64 KB

    if (ws_size >= 2 * bfBytes + sumsBytes) {
        unsigned short* Qbf = (unsigned short*)d_ws;
        unsigned short* Kbf = Qbf + nElem;
        float* sums = (float*)((char*)d_ws + 2 * bfBytes);
        const int half = (int)(nElem / 8 / 256);                    // 4096
        convert_kernel<<<dim3(2 * half), dim3(256), 0, stream>>>(Qp, Kp, Qbf, Kbf, sums);
        // b in blockIdx.x: linear id % 8 == batch -> one batch per XCD (L2 affinity)
        logits_exp_mfma<<<dim3(B_SZ, SEQ / BM, SEQ / BM), dim3(256), 0, stream>>>(Qbf, Kbf, out, sums);
        scale_kernel<<<dim3(B_SZ * SEQ), dim3(256), 0, stream>>>(out, sums);
    } else {
        logits_fallback<<<dim3(SEQ / TS, SEQ / TS, B_SZ), dim3(256), 0, stream>>>(Qp, Kp, out);
        softmax_kernel<<<dim3(B_SZ * SEQ), dim3(256), 0, stream>>>(out);
    }
}

// Round 9
// 230.848 us; speedup vs baseline: 1.0298x; 1.0016x over previous
//
#include <hip/hip_runtime.h>
#include <hip/hip_bf16.h>
#include <math.h>

#define B_SZ 8
#define SEQ 2048
#define DIM 512

typedef __attribute__((ext_vector_type(8))) short bf16x8;
typedef __attribute__((ext_vector_type(8))) unsigned short u16x8;
typedef __attribute__((ext_vector_type(4))) float f32x4;

#define GLOBAL_AS __attribute__((address_space(1)))
#define LDS_AS __attribute__((address_space(3)))

__device__ __forceinline__ unsigned short f2bf(float f) {
    unsigned int u = __builtin_bit_cast(unsigned int, f);
    u += 0x7fffu + ((u >> 16) & 1u);   // RNE
    return (unsigned short)(u >> 16);
}

__device__ __forceinline__ void load_lds16(const void* g, void* l) {
    __builtin_amdgcn_global_load_lds((const GLOBAL_AS unsigned int*)g,
                                     (LDS_AS unsigned int*)l, 16, 0, 0);
}

// ---- fused fp32->bf16 conversion for BOTH tensors + zero the row-sum buffer ----
__global__ __launch_bounds__(256)
void convert_kernel(const float* __restrict__ Q, const float* __restrict__ K,
                    unsigned short* __restrict__ Qb, unsigned short* __restrict__ Kb,
                    float* __restrict__ sums) {
    const int half = (int)(((size_t)B_SZ * SEQ * DIM) / 8 / 256);   // 4096
    const int bid = blockIdx.x;
    const int gi = bid * 256 + threadIdx.x;
    if (gi < B_SZ * SEQ) sums[gi] = 0.f;    // 16384 floats, blocks 0..63

    const float* src;
    unsigned short* dst;
    int i;
    if (bid < half) { src = Q; dst = Qb; i = gi; }
    else            { src = K; dst = Kb; i = gi - half * 256; }

    const float4* s = (const float4*)src;
    float4 a = s[2 * i];
    float4 b = s[2 * i + 1];
    u16x8 o;
    o[0] = f2bf(a.x); o[1] = f2bf(a.y); o[2] = f2bf(a.z); o[3] = f2bf(a.w);
    o[4] = f2bf(b.x); o[5] = f2bf(b.y); o[6] = f2bf(b.z); o[7] = f2bf(b.w);
    ((u16x8*)dst)[i] = o;
}

// ---- m97-structure NT GEMM, 128x128 tile, BK=64, both-sides XOR swizzle ----
// R7 counters: GEMM ran at 2.16 TB/s HBM while writing 135 MB -> the 78us
// duration WAS the write time at 34% write efficiency (64 scalar dword
// stores/thread, 64B segments). R8 fix #1 (swizzle) removed the 6.68M LDS
// conflicts (-6.5us). This round: EPILOGUE VECTORIZATION via LDS bounce --
// after the final barrier the 32KB staging LDS is dead; each wave bounces its
// 16x64 f32 subtile through a private LDS region (row stride 68 words: 272B
// = 17*16B keeps ds_read_b128 aligned; 4*68 % 32 = 16 -> write 2-way = free;
// read spread (q+l16)%8 even -> inherent rate) and stores float4
// (global_store_dwordx4, 256B full segments, 16 stores/thread vs 64).
// blockIdx.x = b -> one batch per XCD (L2 affinity, proven -20us in R4).
#define BM 128
#define BK 64
#define EPS 68   // epilogue LDS row stride in floats
__global__ __launch_bounds__(256)
void logits_exp_mfma(const unsigned short* __restrict__ Qb, const unsigned short* __restrict__ Kb,
                     float* __restrict__ out, float* __restrict__ sums) {
    const int b = blockIdx.x, tk = blockIdx.y, tq = blockIdx.z;
    float* outb = out + (size_t)b * SEQ * SEQ;
    const int t = threadIdx.x;

    if (tk > tq) {
        // strictly-upper tile: final output is exactly 0 here
        const int r0 = t >> 5;          // 0..7
        const int c4 = t & 31;          // 0..31 (float4 column)
        const float4 z = {0.f, 0.f, 0.f, 0.f};
        float* base = outb + (size_t)(tq * BM) * SEQ + tk * BM;
#pragma unroll
        for (int it = 0; it < 16; ++it)
            *(float4*)(base + (size_t)(it * 8 + r0) * SEQ + c4 * 4) = z;
        return;
    }

    // 32 KiB: staging (a:16K | b:16K) during K-loop; reused by epilogue bounce
    __shared__ __align__(16) unsigned char smem[32768];
    unsigned short* a_lds = (unsigned short*)smem;            // [BM*BK]
    unsigned short* b_lds = (unsigned short*)(smem + 16384);  // [BM*BK]

    const int wave = t >> 6;
    const int lane = t & 63;
    const int l16 = lane & 15;
    const int quad = lane >> 4;
    const int wm = wave >> 1;      // 2x2 wave grid, each wave 64x64
    const int wn = wave & 1;

    const unsigned short* Qrow = Qb + ((size_t)b * SEQ + (size_t)tq * BM) * DIM;
    const unsigned short* Krow = Kb + ((size_t)b * SEQ + (size_t)tk * BM) * DIM;

    // staging geometry at BK=64: one global_load_lds = 64 lanes x 16B
    //   = 8 rows x 128B. Pre-swizzled source col-group: g8 ^ sr8.
    const int sr8 = lane >> 3;     // 0..7 row-within-instr
    const int gsw = (lane & 7) ^ sr8;   // swizzled source col-group (16B units)

    f32x4 acc[4][4];
#pragma unroll
    for (int i = 0; i < 4; i++)
#pragma unroll
        for (int j = 0; j < 4; j++) acc[i][j] = (f32x4){0.f, 0.f, 0.f, 0.f};

    for (int k0 = 0; k0 < DIM; k0 += BK) {
#pragma unroll
        for (int j = wave; j < 16; j += 4) {
            int row = j * 8 + sr8;
            load_lds16(Qrow + (size_t)row * DIM + k0 + (gsw << 3), &a_lds[(j * 8) * BK]);
            load_lds16(Krow + (size_t)row * DIM + k0 + (gsw << 3), &b_lds[(j * 8) * BK]);
        }
        __syncthreads();   // drains vmcnt (global_load_lds) + publishes LDS

#pragma unroll
        for (int ks = 0; ks < 2; ++ks) {
            bf16x8 af[4], bfr[4];
#pragma unroll
            for (int mi = 0; mi < 4; mi++) {
                const int row = wm * 64 + mi * 16 + l16;
                const int slot = ((ks << 2) | quad) ^ (row & 7);   // swizzled read
                af[mi] = *(const bf16x8*)&a_lds[row * BK + (slot << 3)];
            }
#pragma unroll
            for (int ni = 0; ni < 4; ni++) {
                const int row = wn * 64 + ni * 16 + l16;
                const int slot = ((ks << 2) | quad) ^ (row & 7);
                bfr[ni] = *(const bf16x8*)&b_lds[row * BK + (slot << 3)];
            }
#pragma unroll
            for (int mi = 0; mi < 4; mi++)
#pragma unroll
                for (int ni = 0; ni < 4; ni++)
                    acc[mi][ni] = __builtin_amdgcn_mfma_f32_16x16x32_bf16(af[mi], bfr[ni], acc[mi][ni], 0, 0, 0);
        }
        __syncthreads();   // LDS reuse guard (also protects epilogue smem reuse)
    }

    // ---- fused epilogue: e = exp(x*scale) (masked on diag tile), LDS bounce
    //      to float4 stores, per-row sum atomics ----
    const float scale = 0.02209708691207961f;  // 1/sqrt(2048)
    const bool diag = (tk == tq);
    float* sums_b = sums + (size_t)b * SEQ;
    float* epw = (float*)smem + wave * (16 * EPS);   // per-wave private region
    const int Rb = tq * BM + wm * 64;
    const int Cb = tk * BM + wn * 64;

#pragma unroll
    for (int mi = 0; mi < 4; mi++) {
#pragma unroll
        for (int r = 0; r < 4; r++) {
            const int row = Rb + mi * 16 + quad * 4 + r;
            float rsum = 0.f;
#pragma unroll
            for (int ni = 0; ni < 4; ni++) {
                const int col = Cb + ni * 16 + l16;
                float e;
                if (diag && col > row) e = 0.f;
                else e = __expf(acc[mi][ni][r] * scale);
                epw[(quad * 4 + r) * EPS + ni * 16 + l16] = e;
                rsum += e;
            }
            // reduce across l16 (xor 1,2,4,8 stays within the 16-lane group)
            rsum += __shfl_xor(rsum, 1);
            rsum += __shfl_xor(rsum, 2);
            rsum += __shfl_xor(rsum, 4);
            rsum += __shfl_xor(rsum, 8);
            if (l16 == 0) atomicAdd(&sums_b[row], rsum);   // device-scope
        }
        // read back float4-contiguous and store dwordx4 (4 rows x 256B / instr)
#pragma unroll
        for (int rr = 0; rr < 4; rr++) {
            const float4 v = *(const float4*)&epw[(rr * 4 + quad) * EPS + l16 * 4];
            *(float4*)(outb + (size_t)(Rb + mi * 16 + rr * 4 + quad) * SEQ + Cb + l16 * 4) = v;
        }
    }
}

// ---- trivial normalization pass: p = e * (1/sum), lower triangle only ----
__global__ __launch_bounds__(256)
void scale_kernel(float* __restrict__ out, const float* __restrict__ sums) {
    const int q = blockIdx.x & (SEQ - 1);
    const int b = blockIdx.x >> 11;
    float* row = out + ((size_t)b * SEQ + q) * SEQ;
    const float inv = 1.0f / sums[blockIdx.x];   // blockIdx.x == b*SEQ + q
    const int n = q + 1;
    const int t = threadIdx.x;
#pragma unroll
    for (int j = 0; j < 2; ++j) {
        int k0 = (t + j * 256) * 4;
        if (k0 < n) {
            float4 x = *(const float4*)(row + k0);
            x.x *= inv; x.y *= inv; x.z *= inv; x.w *= inv;
            *(float4*)(row + k0) = x;   // elements past q in this float4 are e=0 -> stay 0
        }
    }
}

// ==================== small-ws fallback path (round-1 flow) ====================
#define TS 64
#define DC 128
#define LSTRIDE (DC + 8)
__global__ __launch_bounds__(256)
void logits_fallback(const float* __restrict__ Q, const float* __restrict__ K,
                     float* __restrict__ out) {
    const int tk = blockIdx.x, tq = blockIdx.y, b = blockIdx.z;
    if (tk > tq) return;
    __shared__ __align__(16) unsigned short qs[TS * LSTRIDE];
    __shared__ __align__(16) unsigned short ks[TS * LSTRIDE];
    const int t = threadIdx.x;
    const int wave = t >> 6, lane = t & 63, l16 = lane & 15, quad = lane >> 4;
    const float* Qb = Q + ((size_t)b * SEQ + (size_t)tq * TS) * DIM;
    const float* Kb = K + ((size_t)b * SEQ + (size_t)tk * TS) * DIM;
    f32x4 acc[4];
#pragma unroll
    for (int i = 0; i < 4; i++) acc[i] = (f32x4){0.f, 0.f, 0.f, 0.f};
    for (int c = 0; c < DIM; c += DC) {
        __syncthreads();
#pragma unroll
        for (int i = 0; i < 8; i++) {
            int idx = t + i * 256;
            int row = idx >> 5, c4 = idx & 31;
            float4 qv = *(const float4*)(Qb + row * DIM + c + c4 * 4);
            float4 kv = *(const float4*)(Kb + row * DIM + c + c4 * 4);
            ushort4 qh = { f2bf(qv.x), f2bf(qv.y), f2bf(qv.z), f2bf(qv.w) };
            ushort4 kh = { f2bf(kv.x), f2bf(kv.y), f2bf(kv.z), f2bf(kv.w) };
            *(ushort4*)&qs[row * LSTRIDE + c4 * 4] = qh;
            *(ushort4*)&ks[row * LSTRIDE + c4 * 4] = kh;
        }
        __syncthreads();
#pragma unroll
        for (int d = 0; d < DC; d += 32) {
            bf16x8 afrag = *(const bf16x8*)&qs[(wave * 16 + l16) * LSTRIDE + d + quad * 8];
#pragma unroll
            for (int nt = 0; nt < 4; nt++) {
                bf16x8 bfrag = *(const bf16x8*)&ks[(nt * 16 + l16) * LSTRIDE + d + quad * 8];
                acc[nt] = __builtin_amdgcn_mfma_f32_16x16x32_bf16(afrag, bfrag, acc[nt], 0, 0, 0);
            }
        }
    }
    const float scale = 0.02209708691207961f;
    float* outb = out + (size_t)b * SEQ * SEQ;
#pragma unroll
    for (int nt = 0; nt < 4; nt++) {
        int col = tk * TS + nt * 16 + l16;
#pragma unroll
        for (int r = 0; r < 4; r++) {
            int row = tq * TS + wave * 16 + quad * 4 + r;
            outb[(size_t)row * SEQ + col] = acc[nt][r] * scale;
        }
    }
}

__global__ __launch_bounds__(256)
void softmax_kernel(float* __restrict__ out) {
    const int q = blockIdx.x & (SEQ - 1);
    const int b = blockIdx.x >> 11;
    float* row = out + ((size_t)b * SEQ + q) * SEQ;
    const int t = threadIdx.x;
    const int lane = t & 63;
    const int wave = t >> 6;
    const int n = q + 1;

    __shared__ float red[8];

    float4 v[2];
    float m = -INFINITY;
#pragma unroll
    for (int j = 0; j < 2; j++) {
        int k0 = (t + j * 256) * 4;
        if (k0 < n) {
            float4 x = *(const float4*)(row + k0);
            x.y = (k0 + 1 < n) ? x.y : -INFINITY;
            x.z = (k0 + 2 < n) ? x.z : -INFINITY;
            x.w = (k0 + 3 < n) ? x.w : -INFINITY;
            v[j] = x;
            m = fmaxf(m, fmaxf(fmaxf(x.x, x.y), fmaxf(x.z, x.w)));
        } else {
            v[j] = (float4){-INFINITY, -INFINITY, -INFINITY, -INFINITY};
        }
    }
#pragma unroll
    for (int off = 1; off < 64; off <<= 1) m = fmaxf(m, __shfl_xor(m, off));
    if (lane == 0) red[wave] = m;
    __syncthreads();
    m = fmaxf(fmaxf(red[0], red[1]), fmaxf(red[2], red[3]));

    float s = 0.f;
#pragma unroll
    for (int j = 0; j < 2; j++) {
        float4 e;
        e.x = __expf(v[j].x - m);
        e.y = __expf(v[j].y - m);
        e.z = __expf(v[j].z - m);
        e.w = __expf(v[j].w - m);
        v[j] = e;
        s += e.x + e.y + e.z + e.w;
    }
#pragma unroll
    for (int off = 1; off < 64; off <<= 1) s += __shfl_xor(s, off);
    if (lane == 0) red[4 + wave] = s;
    __syncthreads();
    s = red[4] + red[5] + red[6] + red[7];
    const float inv = 1.0f / s;

#pragma unroll
    for (int j = 0; j < 2; j++) {
        int k0 = (t + j * 256) * 4;
        float4 e = v[j];
        e.x *= inv; e.y *= inv; e.z *= inv; e.w *= inv;
        *(float4*)(row + k0) = e;
    }
}

extern "C" void kernel_launch(void* const* d_in, const int* in_sizes, int n_in,
                              void* d_out, int out_size, void* d_ws, size_t ws_size,
                              hipStream_t stream) {
    // setup_inputs order: {"K": ..., "Q": ...}
    const float* Kp = (const float*)d_in[0];
    const float* Qp = (const float*)d_in[1];
    float* out = (float*)d_out;

    const size_t nElem = (size_t)B_SZ * SEQ * DIM;                  // 8.4M per tensor
    const size_t bfBytes = nElem * sizeof(unsigned short);          // 16.8 MB
    const size_t sumsBytes = (size_t)B_SZ * SEQ * sizeof(float);    // 64 KB

    if (ws_size >= 2 * bfBytes + sumsBytes) {
        unsigned short* Qbf = (unsigned short*)d_ws;
        unsigned short* Kbf = Qbf + nElem;
        float* sums = (float*)((char*)d_ws + 2 * bfBytes);
        const int half = (int)(nElem / 8 / 256);                    // 4096
        convert_kernel<<<dim3(2 * half), dim3(256), 0, stream>>>(Qp, Kp, Qbf, Kbf, sums);
        // b in blockIdx.x: linear id % 8 == batch -> one batch per XCD (L2 affinity)
        logits_exp_mfma<<<dim3(B_SZ, SEQ / BM, SEQ / BM), dim3(256), 0, stream>>>(Qbf, Kbf, out, sums);
        scale_kernel<<<dim3(B_SZ * SEQ), dim3(256), 0, stream>>>(out, sums);
    } else {
        logits_fallback<<<dim3(SEQ / TS, SEQ / TS, B_SZ), dim3(256), 0, stream>>>(Qp, Kp, out);
        softmax_kernel<<<dim3(B_SZ * SEQ), dim3(256), 0, stream>>>(out);
    }
}

// Round 10
// 227.368 us; speedup vs baseline: 1.0455x; 1.0153x over previous
//
#include <hip/hip_runtime.h>
#include <hip/hip_bf16.h>
#include <math.h>

#define B_SZ 8
#define SEQ 2048
#define DIM 512

typedef __attribute__((ext_vector_type(8))) short bf16x8;
typedef __attribute__((ext_vector_type(8))) unsigned short u16x8;
typedef __attribute__((ext_vector_type(4))) float f32x4;

#define GLOBAL_AS __attribute__((address_space(1)))
#define LDS_AS __attribute__((address_space(3)))

__device__ __forceinline__ unsigned short f2bf(float f) {
    unsigned int u = __builtin_bit_cast(unsigned int, f);
    u += 0x7fffu + ((u >> 16) & 1u);   // RNE
    return (unsigned short)(u >> 16);
}

__device__ __forceinline__ void load_lds16(const void* g, void* l) {
    __builtin_amdgcn_global_load_lds((const GLOBAL_AS unsigned int*)g,
                                     (LDS_AS unsigned int*)l, 16, 0, 0);
}

// ---- fused fp32->bf16 conversion for BOTH tensors + zero the row-sum buffer ----
__global__ __launch_bounds__(256)
void convert_kernel(const float* __restrict__ Q, const float* __restrict__ K,
                    unsigned short* __restrict__ Qb, unsigned short* __restrict__ Kb,
                    float* __restrict__ sums) {
    const int half = (int)(((size_t)B_SZ * SEQ * DIM) / 8 / 256);   // 4096
    const int bid = blockIdx.x;
    const int gi = bid * 256 + threadIdx.x;
    if (gi < B_SZ * SEQ) sums[gi] = 0.f;    // 16384 floats, blocks 0..63

    const float* src;
    unsigned short* dst;
    int i;
    if (bid < half) { src = Q; dst = Qb; i = gi; }
    else            { src = K; dst = Kb; i = gi - half * 256; }

    const float4* s = (const float4*)src;
    float4 a = s[2 * i];
    float4 b = s[2 * i + 1];
    u16x8 o;
    o[0] = f2bf(a.x); o[1] = f2bf(a.y); o[2] = f2bf(a.z); o[3] = f2bf(a.w);
    o[4] = f2bf(b.x); o[5] = f2bf(b.y); o[6] = f2bf(b.z); o[7] = f2bf(b.w);
    ((u16x8*)dst)[i] = o;
}

// ---- m97-structure NT GEMM, 128x128 tile, BK=32 (proven-best base, R4=227.5us)
// + BOTH-SIDES XOR SWIZZLE (isolated -6.5us on BK=64 in R8), fused exp +
// row-sum epilogue (scalar stores -- vec-epi proven neutral in R9).
// Swizzle (rule #21: linear gload_lds dest + pre-swizzled SOURCE + swizzled READ):
//   staging instr = 16 rows x 64B; source col-group = kg ^ ((sr>>1)&3)
//   fragment read slot = quad ^ ((row>>1)&3)
//   -> ds_read_b128 banks (row%2)*16 + slot*4 take all 8 bank-groups,
//      exactly 2 lanes each (2-way = free, m136) vs 8-way unswizzled.
// blockIdx.x = b -> one batch per XCD (L2 affinity, proven -20us in R4).
#define BM 128
#define BK 32
__global__ __launch_bounds__(256)
void logits_exp_mfma(const unsigned short* __restrict__ Qb, const unsigned short* __restrict__ Kb,
                     float* __restrict__ out, float* __restrict__ sums) {
    const int b = blockIdx.x, tk = blockIdx.y, tq = blockIdx.z;
    float* outb = out + (size_t)b * SEQ * SEQ;
    const int t = threadIdx.x;

    if (tk > tq) {
        // strictly-upper tile: final output is exactly 0 here
        const int r0 = t >> 5;          // 0..7
        const int c4 = t & 31;          // 0..31 (float4 column)
        const float4 z = {0.f, 0.f, 0.f, 0.f};
        float* base = outb + (size_t)(tq * BM) * SEQ + tk * BM;
#pragma unroll
        for (int it = 0; it < 16; ++it)
            *(float4*)(base + (size_t)(it * 8 + r0) * SEQ + c4 * 4) = z;
        return;
    }

    __shared__ __align__(16) unsigned short a_lds[BM * BK];  // 8 KiB
    __shared__ __align__(16) unsigned short b_lds[BM * BK];  // 8 KiB

    const int wave = t >> 6;
    const int lane = t & 63;
    const int l16 = lane & 15;
    const int quad = lane >> 4;
    const int wm = wave >> 1;      // 2x2 wave grid, each wave 64x64
    const int wn = wave & 1;

    const unsigned short* Qrow = Qb + ((size_t)b * SEQ + (size_t)tq * BM) * DIM;
    const unsigned short* Krow = Kb + ((size_t)b * SEQ + (size_t)tk * BM) * DIM;

    // staging geometry: one global_load_lds = 64 lanes x 16B = 16 rows x 64B
    const int sr = lane >> 2;      // 0..15 row-within-instr
    const int kg = lane & 3;       // 0..3  k-group (8 bf16 each)
    const int gsw = kg ^ ((sr >> 1) & 3);   // pre-swizzled source col-group

    f32x4 acc[4][4];
#pragma unroll
    for (int i = 0; i < 4; i++)
#pragma unroll
        for (int j = 0; j < 4; j++) acc[i][j] = (f32x4){0.f, 0.f, 0.f, 0.f};

    for (int k0 = 0; k0 < DIM; k0 += BK) {
#pragma unroll
        for (int j = wave; j < 8; j += 4) {
            int row = j * 16 + sr;
            load_lds16(Qrow + (size_t)row * DIM + k0 + gsw * 8, &a_lds[(j * 16) * BK]);
            load_lds16(Krow + (size_t)row * DIM + k0 + gsw * 8, &b_lds[(j * 16) * BK]);
        }
        __syncthreads();   // drains vmcnt (global_load_lds) + publishes LDS

        bf16x8 af[4], bfr[4];
#pragma unroll
        for (int mi = 0; mi < 4; mi++) {
            const int row = wm * 64 + mi * 16 + l16;
            const int slot = quad ^ ((row >> 1) & 3);   // swizzled read
            af[mi] = *(const bf16x8*)&a_lds[row * BK + slot * 8];
        }
#pragma unroll
        for (int ni = 0; ni < 4; ni++) {
            const int row = wn * 64 + ni * 16 + l16;
            const int slot = quad ^ ((row >> 1) & 3);
            bfr[ni] = *(const bf16x8*)&b_lds[row * BK + slot * 8];
        }
#pragma unroll
        for (int mi = 0; mi < 4; mi++)
#pragma unroll
            for (int ni = 0; ni < 4; ni++)
                acc[mi][ni] = __builtin_amdgcn_mfma_f32_16x16x32_bf16(af[mi], bfr[ni], acc[mi][ni], 0, 0, 0);
        __syncthreads();   // LDS reuse guard
    }

    // ---- fused epilogue: e = exp(x*scale) (masked on diagonal tile),
    //      store e, and atomically accumulate per-row sums ----
    const float scale = 0.02209708691207961f;  // 1/sqrt(2048)
    const bool diag = (tk == tq);
    float* sums_b = sums + (size_t)b * SEQ;

#pragma unroll
    for (int mi = 0; mi < 4; mi++) {
#pragma unroll
        for (int r = 0; r < 4; r++) {
            const int row_l = wm * 64 + mi * 16 + quad * 4 + r;   // 0..127
            const int row = tq * BM + row_l;
            float rsum = 0.f;
#pragma unroll
            for (int ni = 0; ni < 4; ni++) {
                const int col = tk * BM + wn * 64 + ni * 16 + l16;
                float e;
                if (diag && col > row) e = 0.f;
                else e = __expf(acc[mi][ni][r] * scale);
                outb[(size_t)row * SEQ + col] = e;
                rsum += e;
            }
            // reduce across l16 (xor 1,2,4,8 stays within the 16-lane group)
            rsum += __shfl_xor(rsum, 1);
            rsum += __shfl_xor(rsum, 2);
            rsum += __shfl_xor(rsum, 4);
            rsum += __shfl_xor(rsum, 8);
            if (l16 == 0) atomicAdd(&sums_b[row], rsum);   // device-scope
        }
    }
}

// ---- trivial normalization pass: p = e * (1/sum), lower triangle only ----
__global__ __launch_bounds__(256)
void scale_kernel(float* __restrict__ out, const float* __restrict__ sums) {
    const int q = blockIdx.x & (SEQ - 1);
    const int b = blockIdx.x >> 11;
    float* row = out + ((size_t)b * SEQ + q) * SEQ;
    const float inv = 1.0f / sums[blockIdx.x];   // blockIdx.x == b*SEQ + q
    const int n = q + 1;
    const int t = threadIdx.x;
#pragma unroll
    for (int j = 0; j < 2; ++j) {
        int k0 = (t + j * 256) * 4;
        if (k0 < n) {
            float4 x = *(const float4*)(row + k0);
            x.x *= inv; x.y *= inv; x.z *= inv; x.w *= inv;
            *(float4*)(row + k0) = x;   // elements past q in this float4 are e=0 -> stay 0
        }
    }
}

// ==================== small-ws fallback path (round-1 flow) ====================
#define TS 64
#define DC 128
#define LSTRIDE (DC + 8)
__global__ __launch_bounds__(256)
void logits_fallback(const float* __restrict__ Q, const float* __restrict__ K,
                     float* __restrict__ out) {
    const int tk = blockIdx.x, tq = blockIdx.y, b = blockIdx.z;
    if (tk > tq) return;
    __shared__ __align__(16) unsigned short qs[TS * LSTRIDE];
    __shared__ __align__(16) unsigned short ks[TS * LSTRIDE];
    const int t = threadIdx.x;
    const int wave = t >> 6, lane = t & 63, l16 = lane & 15, quad = lane >> 4;
    const float* Qb = Q + ((size_t)b * SEQ + (size_t)tq * TS) * DIM;
    const float* Kb = K + ((size_t)b * SEQ + (size_t)tk * TS) * DIM;
    f32x4 acc[4];
#pragma unroll
    for (int i = 0; i < 4; i++) acc[i] = (f32x4){0.f, 0.f, 0.f, 0.f};
    for (int c = 0; c < DIM; c += DC) {
        __syncthreads();
#pragma unroll
        for (int i = 0; i < 8; i++) {
            int idx = t + i * 256;
            int row = idx >> 5, c4 = idx & 31;
            float4 qv = *(const float4*)(Qb + row * DIM + c + c4 * 4);
            float4 kv = *(const float4*)(Kb + row * DIM + c + c4 * 4);
            ushort4 qh = { f2bf(qv.x), f2bf(qv.y), f2bf(qv.z), f2bf(qv.w) };
            ushort4 kh = { f2bf(kv.x), f2bf(kv.y), f2bf(kv.z), f2bf(kv.w) };
            *(ushort4*)&qs[row * LSTRIDE + c4 * 4] = qh;
            *(ushort4*)&ks[row * LSTRIDE + c4 * 4] = kh;
        }
        __syncthreads();
#pragma unroll
        for (int d = 0; d < DC; d += 32) {
            bf16x8 afrag = *(const bf16x8*)&qs[(wave * 16 + l16) * LSTRIDE + d + quad * 8];
#pragma unroll
            for (int nt = 0; nt < 4; nt++) {
                bf16x8 bfrag = *(const bf16x8*)&ks[(nt * 16 + l16) * LSTRIDE + d + quad * 8];
                acc[nt] = __builtin_amdgcn_mfma_f32_16x16x32_bf16(afrag, bfrag, acc[nt], 0, 0, 0);
            }
        }
    }
    const float scale = 0.02209708691207961f;
    float* outb = out + (size_t)b * SEQ * SEQ;
#pragma unroll
    for (int nt = 0; nt < 4; nt++) {
        int col = tk * TS + nt * 16 + l16;
#pragma unroll
        for (int r = 0; r < 4; r++) {
            int row = tq * TS + wave * 16 + quad * 4 + r;
            outb[(size_t)row * SEQ + col] = acc[nt][r] * scale;
        }
    }
}

__global__ __launch_bounds__(256)
void softmax_kernel(float* __restrict__ out) {
    const int q = blockIdx.x & (SEQ - 1);
    const int b = blockIdx.x >> 11;
    float* row = out + ((size_t)b * SEQ + q) * SEQ;
    const int t = threadIdx.x;
    const int lane = t & 63;
    const int wave = t >> 6;
    const int n = q + 1;

    __shared__ float red[8];

    float4 v[2];
    float m = -INFINITY;
#pragma unroll
    for (int j = 0; j < 2; j++) {
        int k0 = (t + j * 256) * 4;
        if (k0 < n) {
            float4 x = *(const float4*)(row + k0);
            x.y = (k0 + 1 < n) ? x.y : -INFINITY;
            x.z = (k0 + 2 < n) ? x.z : -INFINITY;
            x.w = (k0 + 3 < n) ? x.w : -INFINITY;
            v[j] = x;
            m = fmaxf(m, fmaxf(fmaxf(x.x, x.y), fmaxf(x.z, x.w)));
        } else {
            v[j] = (float4){-INFINITY, -INFINITY, -INFINITY, -INFINITY};
        }
    }
#pragma unroll
    for (int off = 1; off < 64; off <<= 1) m = fmaxf(m, __shfl_xor(m, off));
    if (lane == 0) red[wave] = m;
    __syncthreads();
    m = fmaxf(fmaxf(red[0], red[1]), fmaxf(red[2], red[3]));

    float s = 0.f;
#pragma unroll
    for (int j = 0; j < 2; j++) {
        float4 e;
        e.x = __expf(v[j].x - m);
        e.y = __expf(v[j].y - m);
        e.z = __expf(v[j].z - m);
        e.w = __expf(v[j].w - m);
        v[j] = e;
        s += e.x + e.y + e.z + e.w;
    }
#pragma unroll
    for (int off = 1; off < 64; off <<= 1) s += __shfl_xor(s, off);
    if (lane == 0) red[4 + wave] = s;
    __syncthreads();
    s = red[4] + red[5] + red[6] + red[7];
    const float inv = 1.0f / s;

#pragma unroll
    for (int j = 0; j < 2; j++) {
        int k0 = (t + j * 256) * 4;
        float4 e = v[j];
        e.x *= inv; e.y *= inv; e.z *= inv; e.w *= inv;
        *(float4*)(row + k0) = e;
    }
}

extern "C" void kernel_launch(void* const* d_in, const int* in_sizes, int n_in,
                              void* d_out, int out_size, void* d_ws, size_t ws_size,
                              hipStream_t stream) {
    // setup_inputs order: {"K": ..., "Q": ...}
    const float* Kp = (const float*)d_in[0];
    const float* Qp = (const float*)d_in[1];
    float* out = (float*)d_out;

    const size_t nElem = (size_t)B_SZ * SEQ * DIM;                  // 8.4M per tensor
    const size_t bfBytes = nElem * sizeof(unsigned short);          // 16.8 MB
    const size_t sumsBytes = (size_t)B_SZ * SEQ * sizeof(float);    // 64 KB

    if (ws_size >= 2 * bfBytes + sumsBytes) {
        unsigned short* Qbf = (unsigned short*)d_ws;
        unsigned short* Kbf = Qbf + nElem;
        float* sums = (float*)((char*)d_ws + 2 * bfBytes);
        const int half = (int)(nElem / 8 / 256);                    // 4096
        convert_kernel<<<dim3(2 * half), dim3(256), 0, stream>>>(Qp, Kp, Qbf, Kbf, sums);
        // b in blockIdx.x: linear id % 8 == batch -> one batch per XCD (L2 affinity)
        logits_exp_mfma<<<dim3(B_SZ, SEQ / BM, SEQ / BM), dim3(256), 0, stream>>>(Qbf, Kbf, out, sums);
        scale_kernel<<<dim3(B_SZ * SEQ), dim3(256), 0, stream>>>(out, sums);
    } else {
        logits_fallback<<<dim3(SEQ / TS, SEQ / TS, B_SZ), dim3(256), 0, stream>>>(Qp, Kp, out);
        softmax_kernel<<<dim3(B_SZ * SEQ), dim3(256), 0, stream>>>(out);
    }
}